// Round 2
// baseline (937.963 us; speedup 1.0000x reference)
//
#include <hip/hip_runtime.h>

typedef __bf16 bf16;
typedef bf16 bf16x8 __attribute__((ext_vector_type(8)));
typedef bf16 bf16x4 __attribute__((ext_vector_type(4)));
typedef float f32x4 __attribute__((ext_vector_type(4)));

// B=2, L=1024, D=1024, H=16, HD=64, FFN=2048, TEMP=8, EPS=1e-5. All I/O f32.

// ---------------------------------------------------------------- f32 -> bf16 cast
__global__ __launch_bounds__(256) void kcast(const float* __restrict__ src,
                                             bf16* __restrict__ dst, int n4) {
  int i = blockIdx.x * 256 + threadIdx.x;
  if (i >= n4) return;
  f32x4 v = *(const f32x4*)(src + (long)i * 4);
  bf16x4 o;
#pragma unroll
  for (int j = 0; j < 4; j++) o[j] = (bf16)v[j];
  *(bf16x4*)(dst + (long)i * 4) = o;
}

// ---------------------------------------------------------------- transpose f32 -> bf16
__global__ __launch_bounds__(256) void ktranspose(const float* __restrict__ src,
                                                  bf16* __restrict__ dst, int R, int C) {
  __shared__ float t[32][33];
  int c0 = blockIdx.x * 32, r0 = blockIdx.y * 32;
  int tx = threadIdx.x & 31, ty = threadIdx.x >> 5;  // 32 x 8
#pragma unroll
  for (int i = 0; i < 32; i += 8)
    t[ty + i][tx] = src[(long)(r0 + ty + i) * C + c0 + tx];
  __syncthreads();
#pragma unroll
  for (int i = 0; i < 32; i += 8)
    dst[(long)(c0 + ty + i) * R + r0 + tx] = (bf16)t[tx][ty + i];
}

// ---------------------------------------------------------------- GEMM (C = A * Bt^T), MFMA bf16
// A: M x K bf16 row-major (lda); Bt: N x K bf16 row-major (ldb). 128x128 tile, BK=32, 4 waves.
static constexpr int MODE_QK = 0;       // out bf16 [b,h,l,hd], alpha scale
static constexpr int MODE_VT = 1;       // out bf16 [b,h,hd,l]
static constexpr int MODE_G = 2;        // out f32 = sigmoid(acc + bias[n])
static constexpr int MODE_SCORE = 3;    // out f32 scattered [b,q,k,h] (z = b*16+h)
static constexpr int MODE_PV = 4;       // A=Pws bf16; out bf16 gated
static constexpr int MODE_PV_SLOW = 5;  // A=attn f32 [b,q,k,h] strided; out bf16 gated
static constexpr int MODE_WO = 6;       // out f32 = acc + bias[n]
static constexpr int MODE_FFN1 = 7;     // out bf16 = silu(acc + bias[n])
static constexpr int MODE_FFN2 = 8;     // out f32 = acc + bias[n]

template <int MODE>
__global__ __launch_bounds__(256) void gemm_bt(
    const void* __restrict__ Av, const bf16* __restrict__ Bt, void* __restrict__ Out,
    const float* __restrict__ bias, const float* __restrict__ gate,
    int M, int N, int K, int lda, int ldb, long sA, long sB, float alpha) {
  const int z = blockIdx.z;
  const bf16* A = (const bf16*)Av + (long)z * sA;
  Bt += (long)z * sB;
  const int bb = z >> 4, hh = z & 15;

  __shared__ bf16 As[128][40];
  __shared__ bf16 Bs[128][40];

  const int tid = threadIdx.x;
  const int m0 = blockIdx.y * 128, n0 = blockIdx.x * 128;
  const int lane = tid & 63, wave = tid >> 6;
  const int wm = (wave >> 1) * 64, wn = (wave & 1) * 64;
  const int l15 = lane & 15, quad = lane >> 4;

  f32x4 acc[4][4] = {};

  for (int k0 = 0; k0 < K; k0 += 32) {
    bf16x8 av[2], bv[2];
#pragma unroll
    for (int u = 0; u < 2; u++) {
      int c = tid + u * 256;
      int row = c >> 2, kc = (c & 3) << 3;
      if (MODE == MODE_PV_SLOW) {
        const float* Af = (const float*)Av;
        long rb = ((long)bb << 24) + hh + ((long)(m0 + row) << 14) + ((long)(k0 + kc) << 4);
#pragma unroll
        for (int j = 0; j < 8; j++) av[u][j] = (bf16)Af[rb + j * 16];
      } else {
        av[u] = *(const bf16x8*)(A + (long)(m0 + row) * lda + (k0 + kc));
      }
      int brow = n0 + row;
      if (brow < N) {
        bv[u] = *(const bf16x8*)(Bt + (long)brow * ldb + (k0 + kc));
      } else {
#pragma unroll
        for (int j = 0; j < 8; j++) bv[u][j] = (bf16)0.0f;
      }
    }
    __syncthreads();
#pragma unroll
    for (int u = 0; u < 2; u++) {
      int c = tid + u * 256;
      int row = c >> 2, kc = (c & 3) << 3;
      *(bf16x8*)&As[row][kc] = av[u];
      *(bf16x8*)&Bs[row][kc] = bv[u];
    }
    __syncthreads();

    bf16x8 af[4], bfr[4];
#pragma unroll
    for (int t = 0; t < 4; t++) {
      af[t] = *(const bf16x8*)&As[wm + t * 16 + l15][quad << 3];
      bfr[t] = *(const bf16x8*)&Bs[wn + t * 16 + l15][quad << 3];
    }
#pragma unroll
    for (int mt = 0; mt < 4; mt++)
#pragma unroll
      for (int nt = 0; nt < 4; nt++)
        acc[mt][nt] =
            __builtin_amdgcn_mfma_f32_16x16x32_bf16(af[mt], bfr[nt], acc[mt][nt], 0, 0, 0);
  }

  // C/D layout: col=lane&15, row=quad*4+reg (m89/m91-verified)
#pragma unroll
  for (int mt = 0; mt < 4; mt++) {
#pragma unroll
    for (int nt = 0; nt < 4; nt++) {
#pragma unroll
      for (int r = 0; r < 4; r++) {
        int m = m0 + wm + mt * 16 + (quad << 2) + r;
        int n = n0 + wn + nt * 16 + l15;
        if (n >= N) continue;  // only PV (N=64)
        float v = acc[mt][nt][r] * alpha;
        if (MODE == MODE_QK) {
          long off = ((long)((m >> 10) * 16 + (n >> 6)) * 1024 + (m & 1023)) * 64 + (n & 63);
          ((bf16*)Out)[off] = (bf16)v;
        } else if (MODE == MODE_VT) {
          long off = ((long)((m >> 10) * 16 + (n >> 6)) * 64 + (n & 63)) * 1024 + (m & 1023);
          ((bf16*)Out)[off] = (bf16)v;
        } else if (MODE == MODE_G) {
          float t = v + bias[n];
          ((float*)Out)[(long)m * N + n] = 1.0f / (1.0f + __expf(-t));
        } else if (MODE == MODE_SCORE) {
          long off = ((long)bb << 24) + ((long)m << 14) + ((long)n << 4) + hh;
          ((float*)Out)[off] = v;
        } else if (MODE == MODE_PV || MODE == MODE_PV_SLOW) {
          long off = ((long)(bb * 1024 + m)) * 1024 + hh * 64 + n;
          ((bf16*)Out)[off] = (bf16)(v * gate[off]);
        } else if (MODE == MODE_WO) {
          ((float*)Out)[(long)m * N + n] = v + bias[n];
        } else if (MODE == MODE_FFN1) {
          float t = v + bias[n];
          ((bf16*)Out)[(long)m * N + n] = (bf16)(t / (1.0f + __expf(-t)));
        } else {  // MODE_FFN2
          ((float*)Out)[(long)m * N + n] = v + bias[n];
        }
      }
    }
  }
}

// ---------------------------------------------------------------- bias + softmax (in place)
// One block per (b, q, half): 8 heads. attnf layout [b,q,k,h] f32 (also ebias layout).
__global__ __launch_bounds__(256) void attn_softmax(float* __restrict__ attnf,
                                                    bf16* __restrict__ P_out,
                                                    const float* __restrict__ ebias,
                                                    const unsigned char* __restrict__ mask,
                                                    int write_p) {
  __shared__ float sm[8][1028];
  int bx = blockIdx.x;
  int hb = (bx & 1) * 8;
  int q = (bx >> 1) & 1023;
  int b = bx >> 11;
  int tid = threadIdx.x;
  int lane = tid & 63, wave = tid >> 6;
  long sbase = ((long)b << 24) + ((long)q << 14) + hb;

  for (int i = tid; i < 2048; i += 256) {
    int k = i >> 1, c = (i & 1) * 4;
    long off = sbase + ((long)k << 4) + c;
    f32x4 s = *(const f32x4*)(attnf + off);
    f32x4 e = *(const f32x4*)(ebias + off);
#pragma unroll
    for (int j = 0; j < 4; j++) sm[c + j][k] = s[j] + e[j];
  }
  __syncthreads();

  for (int k = tid; k < 1024; k += 256) {
    if (mask[(b << 10) + k]) {
#pragma unroll
      for (int h = 0; h < 8; h++) sm[h][k] = -1e30f;
    }
  }
  __syncthreads();

  for (int h = wave * 2; h < wave * 2 + 2; h++) {
    float mx = -1e30f;
    for (int k = lane; k < 1024; k += 64) mx = fmaxf(mx, sm[h][k]);
#pragma unroll
    for (int d = 32; d; d >>= 1) mx = fmaxf(mx, __shfl_xor(mx, d, 64));
    float sum = 0.f;
    for (int k = lane; k < 1024; k += 64) {
      float p = __expf(sm[h][k] - mx);
      sm[h][k] = p;
      sum += p;
    }
#pragma unroll
    for (int d = 32; d; d >>= 1) sum += __shfl_xor(sum, d, 64);
    float inv = 1.0f / sum;
    for (int k = lane; k < 1024; k += 64) sm[h][k] *= inv;
  }
  __syncthreads();

  for (int i = tid; i < 2048; i += 256) {
    int k = i >> 1, c = (i & 1) * 4;
    f32x4 v;
#pragma unroll
    for (int j = 0; j < 4; j++) v[j] = sm[c + j][k];
    *(f32x4*)(attnf + sbase + ((long)k << 4) + c) = v;
  }
  if (write_p) {
    for (int i = tid; i < 1024; i += 256) {
      int h = i >> 7, kc = (i & 127) << 3;
      f32x4 lo = *(const f32x4*)&sm[h][kc];
      f32x4 hi = *(const f32x4*)&sm[h][kc + 4];
      bf16x8 v;
#pragma unroll
      for (int j = 0; j < 4; j++) { v[j] = (bf16)lo[j]; v[4 + j] = (bf16)hi[j]; }
      *(bf16x8*)(P_out + ((((long)(b * 16 + hb + h) << 10) + q) << 10) + kc) = v;
    }
  }
}

// ---------------------------------------------------------------- layernorm (1024 cols)
template <int MODE>
__global__ __launch_bounds__(256) void layernorm_k(
    const float* __restrict__ a32, const float* __restrict__ b32, const float* __restrict__ g,
    const float* __restrict__ be, float* __restrict__ of32, bf16* __restrict__ obf) {
  __shared__ float red[8];
  long base = (long)blockIdx.x << 10;
  int tid = threadIdx.x;
  int lane = tid & 63, wave = tid >> 6;
  float h[4], sum = 0.f, sq = 0.f;
#pragma unroll
  for (int t = 0; t < 4; t++) {
    int i = tid + t * 256;
    float v = a32[base + i] + b32[base + i];
    h[t] = v;
    sum += v;
    sq += v * v;
  }
#pragma unroll
  for (int d = 32; d; d >>= 1) {
    sum += __shfl_xor(sum, d, 64);
    sq += __shfl_xor(sq, d, 64);
  }
  if (lane == 0) { red[wave] = sum; red[4 + wave] = sq; }
  __syncthreads();
  sum = red[0] + red[1] + red[2] + red[3];
  sq = red[4] + red[5] + red[6] + red[7];
  float mean = sum * (1.0f / 1024.0f);
  float var = sq * (1.0f / 1024.0f) - mean * mean;
  float rstd = rsqrtf(var + 1e-5f);
#pragma unroll
  for (int t = 0; t < 4; t++) {
    int i = tid + t * 256;
    float o = (h[t] - mean) * rstd * g[i] + be[i];
    of32[base + i] = o;
    if (MODE == 0) obf[base + i] = (bf16)o;
  }
}

// ---------------------------------------------------------------- launch
extern "C" void kernel_launch(void* const* d_in, const int* in_sizes, int n_in, void* d_out,
                              int out_size, void* d_ws, size_t ws_size, hipStream_t stream) {
  const float* x = (const float*)d_in[0];
  const float* ebias = (const float*)d_in[1];
  const unsigned char* pmask = (const unsigned char*)d_in[2];
  const float* wq = (const float*)d_in[3];
  const float* wk = (const float*)d_in[4];
  const float* wv = (const float*)d_in[5];
  const float* wo = (const float*)d_in[6];
  const float* bo = (const float*)d_in[7];
  const float* wg = (const float*)d_in[8];
  const float* bg = (const float*)d_in[9];
  const float* w1 = (const float*)d_in[10];
  const float* b1 = (const float*)d_in[11];
  const float* w2 = (const float*)d_in[12];
  const float* b2 = (const float*)d_in[13];
  const float* ln1g = (const float*)d_in[14];
  const float* ln1b = (const float*)d_in[15];
  const float* ln2g = (const float*)d_in[16];
  const float* ln2b = (const float*)d_in[17];

  char* p = (char*)d_ws;
  bf16* xbf = (bf16*)p;  p += 4194304;    // x cast (2048x1024)
  bf16* wqT = (bf16*)p;  p += 2097152;
  bf16* wkT = (bf16*)p;  p += 2097152;
  bf16* wvT = (bf16*)p;  p += 2097152;
  bf16* wgT = (bf16*)p;  p += 2097152;
  bf16* woT = (bf16*)p;  p += 2097152;
  bf16* w1T = (bf16*)p;  p += 4194304;    // (2048,1024)
  bf16* w2T = (bf16*)p;  p += 4194304;    // (1024,2048)
  bf16* qws = (bf16*)p;  p += 4194304;    // [b,h,l,hd]
  bf16* kws = (bf16*)p;  p += 4194304;    // [b,h,l,hd]
  bf16* vtws = (bf16*)p; p += 4194304;    // [b,h,hd,l]
  float* gws = (float*)p; p += 8388608;   // sigmoid gate (2048x1024) f32
  bf16* ows = (bf16*)p;  p += 4194304;    // gated attn out bf16
  float* delta = (float*)p; p += 8388608;
  bf16* x1bf = (bf16*)p; p += 4194304;
  float* x1f = (float*)p; p += 8388608;
  bf16* ffn1 = (bf16*)p; p += 8388608;    // (2048,2048) bf16
  float* ffn2 = (float*)p; p += 8388608;
  size_t base_used = (size_t)(p - (char*)d_ws);
  bf16* Pws = (bf16*)p;                   // optional 64MB: probs bf16 [b,h,q,k]
  bool pv_fast = (base_used + 67108864ull) <= ws_size;

  float* xout = (float*)d_out;
  float* attnf = (float*)d_out + 2097152;  // [b,q,k,h] f32: scores, then probs

  dim3 blk(256);

  kcast<<<2048, blk, 0, stream>>>(x, xbf, 524288);
  ktranspose<<<dim3(32, 32), blk, 0, stream>>>(wq, wqT, 1024, 1024);
  ktranspose<<<dim3(32, 32), blk, 0, stream>>>(wk, wkT, 1024, 1024);
  ktranspose<<<dim3(32, 32), blk, 0, stream>>>(wv, wvT, 1024, 1024);
  ktranspose<<<dim3(32, 32), blk, 0, stream>>>(wg, wgT, 1024, 1024);
  ktranspose<<<dim3(32, 32), blk, 0, stream>>>(wo, woT, 1024, 1024);
  ktranspose<<<dim3(64, 32), blk, 0, stream>>>(w1, w1T, 1024, 2048);
  ktranspose<<<dim3(32, 64), blk, 0, stream>>>(w2, w2T, 2048, 1024);

  // projections (M=2048, N=1024, K=1024)
  gemm_bt<MODE_QK><<<dim3(8, 16, 1), blk, 0, stream>>>(xbf, wqT, qws, nullptr, nullptr, 2048,
                                                       1024, 1024, 1024, 1024, 0, 0, 0.125f);
  gemm_bt<MODE_QK><<<dim3(8, 16, 1), blk, 0, stream>>>(xbf, wkT, kws, nullptr, nullptr, 2048,
                                                       1024, 1024, 1024, 1024, 0, 0, 1.0f);
  gemm_bt<MODE_VT><<<dim3(8, 16, 1), blk, 0, stream>>>(xbf, wvT, vtws, nullptr, nullptr, 2048,
                                                       1024, 1024, 1024, 1024, 0, 0, 1.0f);
  gemm_bt<MODE_G><<<dim3(8, 16, 1), blk, 0, stream>>>(xbf, wgT, gws, bg, nullptr, 2048, 1024,
                                                      1024, 1024, 1024, 0, 0, 1.0f);

  // scores -> attnf [b,q,k,h] f32 (per (b,h): 1024x1024, K=64)
  gemm_bt<MODE_SCORE><<<dim3(8, 8, 32), blk, 0, stream>>>(qws, kws, attnf, nullptr, nullptr, 1024,
                                                          1024, 64, 64, 64, 65536, 65536, 1.0f);
  // bias + softmax in place; emit P bf16 if ws allows
  attn_softmax<<<4096, blk, 0, stream>>>(attnf, pv_fast ? Pws : nullptr, ebias, pmask,
                                         pv_fast ? 1 : 0);

  // PV (per (b,h): 1024x64, K=1024), fused gate
  if (pv_fast) {
    gemm_bt<MODE_PV><<<dim3(1, 8, 32), blk, 0, stream>>>(Pws, vtws, ows, nullptr, gws, 1024, 64,
                                                         1024, 1024, 1024, 1048576, 65536, 1.0f);
  } else {
    gemm_bt<MODE_PV_SLOW><<<dim3(1, 8, 32), blk, 0, stream>>>(attnf, vtws, ows, nullptr, gws,
                                                              1024, 64, 1024, 1024, 1024, 0,
                                                              65536, 1.0f);
  }

  // delta = o @ wo + bo
  gemm_bt<MODE_WO><<<dim3(8, 16, 1), blk, 0, stream>>>(ows, woT, delta, bo, nullptr, 2048, 1024,
                                                       1024, 1024, 1024, 0, 0, 1.0f);
  // x1 = LN1(x + delta)
  layernorm_k<0><<<2048, blk, 0, stream>>>(x, delta, ln1g, ln1b, x1f, x1bf);
  // ffn1 = silu(x1 @ w1 + b1)
  gemm_bt<MODE_FFN1><<<dim3(16, 16, 1), blk, 0, stream>>>(x1bf, w1T, ffn1, b1, nullptr, 2048,
                                                          2048, 1024, 1024, 1024, 0, 0, 1.0f);
  // ffn2 = ffn1 @ w2 + b2
  gemm_bt<MODE_FFN2><<<dim3(8, 16, 1), blk, 0, stream>>>(ffn1, w2T, ffn2, b2, nullptr, 2048, 1024,
                                                         2048, 2048, 2048, 0, 0, 1.0f);
  // out = LN2(x1 + ffn2)
  layernorm_k<1><<<2048, blk, 0, stream>>>(x1f, ffn2, ln2g, ln2b, xout, nullptr);
}

// Round 3
// 674.353 us; speedup vs baseline: 1.3909x; 1.3909x over previous
//
#include <hip/hip_runtime.h>

typedef __bf16 bf16;
typedef _Float16 f16;
typedef bf16 bf16x8 __attribute__((ext_vector_type(8)));
typedef bf16 bf16x4 __attribute__((ext_vector_type(4)));
typedef f16 f16x4 __attribute__((ext_vector_type(4)));
typedef float f32x4 __attribute__((ext_vector_type(4)));

// B=2, L=1024, D=1024, H=16, HD=64, FFN=2048, TEMP=8, EPS=1e-5. All I/O f32.

// ---------------------------------------------------------------- f32 -> bf16 cast
__global__ __launch_bounds__(256) void kcast(const float* __restrict__ src,
                                             bf16* __restrict__ dst, int n4) {
  int i = blockIdx.x * 256 + threadIdx.x;
  if (i >= n4) return;
  f32x4 v = *(const f32x4*)(src + (long)i * 4);
  bf16x4 o;
#pragma unroll
  for (int j = 0; j < 4; j++) o[j] = (bf16)v[j];
  *(bf16x4*)(dst + (long)i * 4) = o;
}

// ---------------------------------------------------------------- transpose f32 -> bf16
__global__ __launch_bounds__(256) void ktranspose(const float* __restrict__ src,
                                                  bf16* __restrict__ dst, int R, int C) {
  __shared__ float t[32][33];
  int c0 = blockIdx.x * 32, r0 = blockIdx.y * 32;
  int tx = threadIdx.x & 31, ty = threadIdx.x >> 5;  // 32 x 8
#pragma unroll
  for (int i = 0; i < 32; i += 8)
    t[ty + i][tx] = src[(long)(r0 + ty + i) * C + c0 + tx];
  __syncthreads();
#pragma unroll
  for (int i = 0; i < 32; i += 8)
    dst[(long)(c0 + ty + i) * R + r0 + tx] = (bf16)t[tx][ty + i];
}

// ---------------------------------------------------------------- GEMM (C = A * Bt^T), MFMA bf16
static constexpr int MODE_QK = 0;        // out bf16 [b,h,l,hd], alpha scale
static constexpr int MODE_VT = 1;        // out bf16 [b,h,hd,l]
static constexpr int MODE_G = 2;         // out f32 = sigmoid(acc + bias[n])
static constexpr int MODE_SCOREF16 = 3;  // out f16 [b,h,q,k] contiguous (z = b*16+h)
static constexpr int MODE_SCORE_SC = 4;  // out f32 scattered [b,q,k,h] (fallback)
static constexpr int MODE_PV = 5;        // A=Pws bf16 [b,h,q,k]; out bf16 gated
static constexpr int MODE_PV_SLOW = 6;   // A=attn f32 [b,q,k,h] strided; out bf16 gated
static constexpr int MODE_WO = 7;        // out f32 = acc + bias[n]
static constexpr int MODE_FFN1 = 8;      // out bf16 = silu(acc + bias[n])
static constexpr int MODE_FFN2 = 9;      // out f32 = acc + bias[n]

template <int MODE>
__global__ __launch_bounds__(256) void gemm_bt(
    const void* __restrict__ Av, const bf16* __restrict__ Bt, void* __restrict__ Out,
    const float* __restrict__ bias, const float* __restrict__ gate,
    int M, int N, int K, int lda, int ldb, long sA, long sB, float alpha) {
  const int z = blockIdx.z;
  const bf16* A = (const bf16*)Av + (long)z * sA;
  Bt += (long)z * sB;
  const int bb = z >> 4, hh = z & 15;

  __shared__ bf16 As[128][40];  // 80B row stride -> 2-way (free) on ds_read_b128
  __shared__ bf16 Bs[128][40];

  const int tid = threadIdx.x;
  const int m0 = blockIdx.y * 128, n0 = blockIdx.x * 128;
  const int lane = tid & 63, wave = tid >> 6;
  const int wm = (wave >> 1) * 64, wn = (wave & 1) * 64;
  const int l15 = lane & 15, quad = lane >> 4;

  f32x4 acc[4][4] = {};

  for (int k0 = 0; k0 < K; k0 += 32) {
    bf16x8 av[2], bv[2];
#pragma unroll
    for (int u = 0; u < 2; u++) {
      int c = tid + u * 256;
      int row = c >> 2, kc = (c & 3) << 3;
      if (MODE == MODE_PV_SLOW) {
        const float* Af = (const float*)Av;
        long rb = ((long)bb << 24) + hh + ((long)(m0 + row) << 14) + ((long)(k0 + kc) << 4);
#pragma unroll
        for (int j = 0; j < 8; j++) av[u][j] = (bf16)Af[rb + j * 16];
      } else {
        av[u] = *(const bf16x8*)(A + (long)(m0 + row) * lda + (k0 + kc));
      }
      int brow = n0 + row;
      if (brow < N) {
        bv[u] = *(const bf16x8*)(Bt + (long)brow * ldb + (k0 + kc));
      } else {
#pragma unroll
        for (int j = 0; j < 8; j++) bv[u][j] = (bf16)0.0f;
      }
    }
    __syncthreads();
#pragma unroll
    for (int u = 0; u < 2; u++) {
      int c = tid + u * 256;
      int row = c >> 2, kc = (c & 3) << 3;
      *(bf16x8*)&As[row][kc] = av[u];
      *(bf16x8*)&Bs[row][kc] = bv[u];
    }
    __syncthreads();

    bf16x8 af[4], bfr[4];
#pragma unroll
    for (int t = 0; t < 4; t++) {
      af[t] = *(const bf16x8*)&As[wm + t * 16 + l15][quad << 3];
      bfr[t] = *(const bf16x8*)&Bs[wn + t * 16 + l15][quad << 3];
    }
#pragma unroll
    for (int mt = 0; mt < 4; mt++)
#pragma unroll
      for (int nt = 0; nt < 4; nt++)
        acc[mt][nt] =
            __builtin_amdgcn_mfma_f32_16x16x32_bf16(af[mt], bfr[nt], acc[mt][nt], 0, 0, 0);
  }

  // C/D layout: col=lane&15, row=quad*4+reg
#pragma unroll
  for (int mt = 0; mt < 4; mt++) {
#pragma unroll
    for (int nt = 0; nt < 4; nt++) {
#pragma unroll
      for (int r = 0; r < 4; r++) {
        int m = m0 + wm + mt * 16 + (quad << 2) + r;
        int n = n0 + wn + nt * 16 + l15;
        if (n >= N) continue;  // only PV (N=64)
        float v = acc[mt][nt][r] * alpha;
        if (MODE == MODE_QK) {
          long off = ((long)((m >> 10) * 16 + (n >> 6)) * 1024 + (m & 1023)) * 64 + (n & 63);
          ((bf16*)Out)[off] = (bf16)v;
        } else if (MODE == MODE_VT) {
          long off = ((long)((m >> 10) * 16 + (n >> 6)) * 64 + (n & 63)) * 1024 + (m & 1023);
          ((bf16*)Out)[off] = (bf16)v;
        } else if (MODE == MODE_G) {
          float t = v + bias[n];
          ((float*)Out)[(long)m * N + n] = 1.0f / (1.0f + __expf(-t));
        } else if (MODE == MODE_SCOREF16) {
          ((f16*)Out)[((long)z << 20) + ((long)m << 10) + n] = (f16)v;
        } else if (MODE == MODE_SCORE_SC) {
          long off = ((long)bb << 24) + ((long)m << 14) + ((long)n << 4) + hh;
          ((float*)Out)[off] = v;
        } else if (MODE == MODE_PV || MODE == MODE_PV_SLOW) {
          long off = ((long)(bb * 1024 + m)) * 1024 + hh * 64 + n;
          ((bf16*)Out)[off] = (bf16)(v * gate[off]);
        } else if (MODE == MODE_WO) {
          ((float*)Out)[(long)m * N + n] = v + bias[n];
        } else if (MODE == MODE_FFN1) {
          float t = v + bias[n];
          ((bf16*)Out)[(long)m * N + n] = (bf16)(t / (1.0f + __expf(-t)));
        } else {  // MODE_FFN2
          ((float*)Out)[(long)m * N + n] = v + bias[n];
        }
      }
    }
  }
}

// ---------------------------------------------------------------- bias + softmax
// FAST=1: scores f16 [b,h,q,k] in Sf; probs written bf16 IN PLACE (same bytes) + attn f32.
// FAST=0: scores f32 scattered in attnf [b,q,k,h]; probs rewritten there in place.
// One block per (b, q, half): 8 heads, 32KB LDS.
template <int FAST>
__global__ __launch_bounds__(256) void attn_softmax(float* __restrict__ attnf,
                                                    void* __restrict__ Sf,
                                                    const float* __restrict__ ebias,
                                                    const unsigned char* __restrict__ mask) {
  __shared__ float sm[8][1028];
  int bx = blockIdx.x;
  int hb = (bx & 1) * 8;
  int q = (bx >> 1) & 1023;
  int b = bx >> 11;
  int tid = threadIdx.x;
  int lane = tid & 63, wave = tid >> 6;
  long sbase = ((long)b << 24) + ((long)q << 14) + hb;  // [b,q,k,h] slice base

  if (FAST) {
    for (int i = tid; i < 2048; i += 256) {
      int h = i >> 8, kc = (i & 255) << 2;
      long rb = (((long)(b * 16 + hb + h) << 10) + q) << 10;
      f16x4 v = *(const f16x4*)((const f16*)Sf + rb + kc);
#pragma unroll
      for (int j = 0; j < 4; j++) sm[h][kc + j] = (float)v[j];
    }
    __syncthreads();
    for (int i = tid; i < 2048; i += 256) {
      int k = i >> 1, c = (i & 1) * 4;
      f32x4 e = *(const f32x4*)(ebias + sbase + ((long)k << 4) + c);
#pragma unroll
      for (int j = 0; j < 4; j++) sm[c + j][k] += e[j];
    }
  } else {
    for (int i = tid; i < 2048; i += 256) {
      int k = i >> 1, c = (i & 1) * 4;
      long off = sbase + ((long)k << 4) + c;
      f32x4 s = *(const f32x4*)(attnf + off);
      f32x4 e = *(const f32x4*)(ebias + off);
#pragma unroll
      for (int j = 0; j < 4; j++) sm[c + j][k] = s[j] + e[j];
    }
  }
  __syncthreads();

  for (int k = tid; k < 1024; k += 256) {
    if (mask[(b << 10) + k]) {
#pragma unroll
      for (int h = 0; h < 8; h++) sm[h][k] = -1e30f;
    }
  }
  __syncthreads();

  for (int h = wave * 2; h < wave * 2 + 2; h++) {
    float mx = -1e30f;
    for (int k = lane; k < 1024; k += 64) mx = fmaxf(mx, sm[h][k]);
#pragma unroll
    for (int d = 32; d; d >>= 1) mx = fmaxf(mx, __shfl_xor(mx, d, 64));
    float sum = 0.f;
    for (int k = lane; k < 1024; k += 64) {
      float p = __expf(sm[h][k] - mx);
      sm[h][k] = p;
      sum += p;
    }
#pragma unroll
    for (int d = 32; d; d >>= 1) sum += __shfl_xor(sum, d, 64);
    float inv = 1.0f / sum;
    for (int k = lane; k < 1024; k += 64) sm[h][k] *= inv;
  }
  __syncthreads();

  // attn_out probs f32 [b,q,k,h] (coalesced)
  for (int i = tid; i < 2048; i += 256) {
    int k = i >> 1, c = (i & 1) * 4;
    f32x4 v;
#pragma unroll
    for (int j = 0; j < 4; j++) v[j] = sm[c + j][k];
    *(f32x4*)(attnf + sbase + ((long)k << 4) + c) = v;
  }
  if (FAST) {  // P bf16 [b,h,q,k], in place over the f16 scores (same slice, post-barrier safe)
    for (int i = tid; i < 2048; i += 256) {
      int h = i >> 8, kc = (i & 255) << 2;
      long rb = (((long)(b * 16 + hb + h) << 10) + q) << 10;
      bf16x4 v;
#pragma unroll
      for (int j = 0; j < 4; j++) v[j] = (bf16)sm[h][kc + j];
      *(bf16x4*)((bf16*)Sf + rb + kc) = v;
    }
  }
}

// ---------------------------------------------------------------- layernorm (1024 cols)
template <int MODE>
__global__ __launch_bounds__(256) void layernorm_k(
    const float* __restrict__ a32, const float* __restrict__ b32, const float* __restrict__ g,
    const float* __restrict__ be, float* __restrict__ of32, bf16* __restrict__ obf) {
  __shared__ float red[8];
  long base = (long)blockIdx.x << 10;
  int tid = threadIdx.x;
  int lane = tid & 63, wave = tid >> 6;
  float h[4], sum = 0.f, sq = 0.f;
#pragma unroll
  for (int t = 0; t < 4; t++) {
    int i = tid + t * 256;
    float v = a32[base + i] + b32[base + i];
    h[t] = v;
    sum += v;
    sq += v * v;
  }
#pragma unroll
  for (int d = 32; d; d >>= 1) {
    sum += __shfl_xor(sum, d, 64);
    sq += __shfl_xor(sq, d, 64);
  }
  if (lane == 0) { red[wave] = sum; red[4 + wave] = sq; }
  __syncthreads();
  sum = red[0] + red[1] + red[2] + red[3];
  sq = red[4] + red[5] + red[6] + red[7];
  float mean = sum * (1.0f / 1024.0f);
  float var = sq * (1.0f / 1024.0f) - mean * mean;
  float rstd = rsqrtf(var + 1e-5f);
#pragma unroll
  for (int t = 0; t < 4; t++) {
    int i = tid + t * 256;
    float o = (h[t] - mean) * rstd * g[i] + be[i];
    of32[base + i] = o;
    if (MODE == 0) obf[base + i] = (bf16)o;
  }
}

// ---------------------------------------------------------------- launch
extern "C" void kernel_launch(void* const* d_in, const int* in_sizes, int n_in, void* d_out,
                              int out_size, void* d_ws, size_t ws_size, hipStream_t stream) {
  const float* x = (const float*)d_in[0];
  const float* ebias = (const float*)d_in[1];
  const unsigned char* pmask = (const unsigned char*)d_in[2];
  const float* wq = (const float*)d_in[3];
  const float* wk = (const float*)d_in[4];
  const float* wv = (const float*)d_in[5];
  const float* wo = (const float*)d_in[6];
  const float* bo = (const float*)d_in[7];
  const float* wg = (const float*)d_in[8];
  const float* bg = (const float*)d_in[9];
  const float* w1 = (const float*)d_in[10];
  const float* b1 = (const float*)d_in[11];
  const float* w2 = (const float*)d_in[12];
  const float* b2 = (const float*)d_in[13];
  const float* ln1g = (const float*)d_in[14];
  const float* ln1b = (const float*)d_in[15];
  const float* ln2g = (const float*)d_in[16];
  const float* ln2b = (const float*)d_in[17];

  char* p = (char*)d_ws;
  bf16* xbf = (bf16*)p;  p += 4194304;
  bf16* wqT = (bf16*)p;  p += 2097152;
  bf16* wkT = (bf16*)p;  p += 2097152;
  bf16* wvT = (bf16*)p;  p += 2097152;
  bf16* wgT = (bf16*)p;  p += 2097152;
  bf16* woT = (bf16*)p;  p += 2097152;
  bf16* w1T = (bf16*)p;  p += 4194304;
  bf16* w2T = (bf16*)p;  p += 4194304;
  bf16* qws = (bf16*)p;  p += 4194304;    // [b,h,l,hd]
  bf16* kws = (bf16*)p;  p += 4194304;    // [b,h,l,hd]
  bf16* vtws = (bf16*)p; p += 4194304;    // [b,h,hd,l]
  float* gws = (float*)p; p += 8388608;   // sigmoid gate f32
  bf16* ows = (bf16*)p;  p += 4194304;
  float* delta = (float*)p; p += 8388608;
  bf16* x1bf = (bf16*)p; p += 4194304;
  float* x1f = (float*)p; p += 8388608;
  bf16* ffn1 = (bf16*)p; p += 8388608;
  float* ffn2 = (float*)p; p += 8388608;
  size_t base_used = (size_t)(p - (char*)d_ws);
  void* Pws = (void*)p;  // 64MB: f16 scores [b,h,q,k], then bf16 probs in place
  bool fast = (base_used + 67108864ull) <= ws_size;

  float* xout = (float*)d_out;
  float* attnf = (float*)d_out + 2097152;  // output 1: [b,q,k,h] f32

  dim3 blk(256);

  kcast<<<2048, blk, 0, stream>>>(x, xbf, 524288);
  ktranspose<<<dim3(32, 32), blk, 0, stream>>>(wq, wqT, 1024, 1024);
  ktranspose<<<dim3(32, 32), blk, 0, stream>>>(wk, wkT, 1024, 1024);
  ktranspose<<<dim3(32, 32), blk, 0, stream>>>(wv, wvT, 1024, 1024);
  ktranspose<<<dim3(32, 32), blk, 0, stream>>>(wg, wgT, 1024, 1024);
  ktranspose<<<dim3(32, 32), blk, 0, stream>>>(wo, woT, 1024, 1024);
  ktranspose<<<dim3(64, 32), blk, 0, stream>>>(w1, w1T, 1024, 2048);
  ktranspose<<<dim3(32, 64), blk, 0, stream>>>(w2, w2T, 2048, 1024);

  // projections (M=2048, N=1024, K=1024)
  gemm_bt<MODE_QK><<<dim3(8, 16, 1), blk, 0, stream>>>(xbf, wqT, qws, nullptr, nullptr, 2048,
                                                       1024, 1024, 1024, 1024, 0, 0, 0.125f);
  gemm_bt<MODE_QK><<<dim3(8, 16, 1), blk, 0, stream>>>(xbf, wkT, kws, nullptr, nullptr, 2048,
                                                       1024, 1024, 1024, 1024, 0, 0, 1.0f);
  gemm_bt<MODE_VT><<<dim3(8, 16, 1), blk, 0, stream>>>(xbf, wvT, vtws, nullptr, nullptr, 2048,
                                                       1024, 1024, 1024, 1024, 0, 0, 1.0f);
  gemm_bt<MODE_G><<<dim3(8, 16, 1), blk, 0, stream>>>(xbf, wgT, gws, bg, nullptr, 2048, 1024,
                                                      1024, 1024, 1024, 0, 0, 1.0f);

  if (fast) {
    // scores f16, coalesced [b,h,q,k]
    gemm_bt<MODE_SCOREF16><<<dim3(8, 8, 32), blk, 0, stream>>>(
        qws, kws, Pws, nullptr, nullptr, 1024, 1024, 64, 64, 64, 65536, 65536, 1.0f);
    attn_softmax<1><<<4096, blk, 0, stream>>>(attnf, Pws, ebias, pmask);
    gemm_bt<MODE_PV><<<dim3(1, 8, 32), blk, 0, stream>>>((bf16*)Pws, vtws, ows, nullptr, gws,
                                                         1024, 64, 1024, 1024, 1024, 1048576,
                                                         65536, 1.0f);
  } else {
    gemm_bt<MODE_SCORE_SC><<<dim3(8, 8, 32), blk, 0, stream>>>(
        qws, kws, attnf, nullptr, nullptr, 1024, 1024, 64, 64, 64, 65536, 65536, 1.0f);
    attn_softmax<0><<<4096, blk, 0, stream>>>(attnf, nullptr, ebias, pmask);
    gemm_bt<MODE_PV_SLOW><<<dim3(1, 8, 32), blk, 0, stream>>>(attnf, vtws, ows, nullptr, gws,
                                                              1024, 64, 1024, 1024, 1024, 0,
                                                              65536, 1.0f);
  }

  // delta = o @ wo + bo
  gemm_bt<MODE_WO><<<dim3(8, 16, 1), blk, 0, stream>>>(ows, woT, delta, bo, nullptr, 2048, 1024,
                                                       1024, 1024, 1024, 0, 0, 1.0f);
  // x1 = LN1(x + delta)
  layernorm_k<0><<<2048, blk, 0, stream>>>(x, delta, ln1g, ln1b, x1f, x1bf);
  // ffn1 = silu(x1 @ w1 + b1)
  gemm_bt<MODE_FFN1><<<dim3(16, 16, 1), blk, 0, stream>>>(x1bf, w1T, ffn1, b1, nullptr, 2048,
                                                          2048, 1024, 1024, 1024, 0, 0, 1.0f);
  // ffn2 = ffn1 @ w2 + b2
  gemm_bt<MODE_FFN2><<<dim3(8, 16, 1), blk, 0, stream>>>(ffn1, w2T, ffn2, b2, nullptr, 2048, 1024,
                                                         2048, 2048, 2048, 0, 0, 1.0f);
  // out = LN2(x1 + ffn2)
  layernorm_k<1><<<2048, blk, 0, stream>>>(x1f, ffn2, ln2g, ln2b, xout, nullptr);
}